// Round 17
// baseline (594.606 us; speedup 1.0000x reference)
//
#include <hip/hip_runtime.h>
#include <math.h>

// Problem constants
#define BB 4
#define SS 64
#define NN 256
#define FF 32
#define HH 64
#define MM (BB*SS)      // 256 graphs
#define NSEQ (BB*NN)    // 1024 sequences
#define TT SS           // 64 timesteps

// fast activations: v_rcp_f32 (~1ulp) instead of IEEE divide
__device__ __forceinline__ float fast_rcp(float x) { return __builtin_amdgcn_rcpf(x); }
__device__ __forceinline__ float sigmoid_f(float x) { return fast_rcp(1.0f + __expf(-x)); }
__device__ __forceinline__ float tanh_f(float x) {
    float t = __expf(-2.0f * fabsf(x));
    float r = (1.0f - t) * fast_rcp(1.0f + t);
    return copysignf(r, x);
}

// LDS-only barrier: waits ONLY lgkmcnt (LDS) before s_barrier, leaving global
// prefetch loads / stores IN FLIGHT across the barrier.
__device__ __forceinline__ void lds_barrier() {
    asm volatile("s_waitcnt lgkmcnt(0)" ::: "memory");
    __builtin_amdgcn_s_barrier();
    __builtin_amdgcn_sched_barrier(0);
}

// ---- bf16 split helpers (RTNE hi, hi+lo captures ~17 mantissa bits) ----
typedef __bf16 bf16x8 __attribute__((ext_vector_type(8)));
typedef float  f32x4  __attribute__((ext_vector_type(4)));

__device__ __forceinline__ __bf16 bfh(float x) {
    unsigned u = __float_as_uint(x);
    unsigned r = (u + 0x7FFFu + ((u >> 16) & 1u)) >> 16;
    return __builtin_bit_cast(__bf16, (unsigned short)r);
}
__device__ __forceinline__ float bf2f(__bf16 b) {
    unsigned u = ((unsigned)__builtin_bit_cast(unsigned short, b)) << 16;
    return __uint_as_float(u);
}

// ---------------------------------------------------------------------------
// GAT layer v4 (unchanged from r15): MFMA aggregation, 512 threads.
// ---------------------------------------------------------------------------
template<int FIN>
__global__ __launch_bounds__(512) void gat_kernel(
    const float* __restrict__ xin,   // [M][N][FIN]
    const float* __restrict__ adj,   // [M][N][N]
    const float* __restrict__ W,     // [FIN][64]
    const float* __restrict__ a,     // [128]
    const float* __restrict__ gamma_, const float* __restrict__ beta_,
    float* __restrict__ gout)        // [M][N][64]
{
    __shared__ __align__(16) float u_f32[256 * 68];     // 69632 B, reused as F
    __shared__ __align__(16) __bf16 p_hi[256 * 40];
    __shared__ __align__(16) __bf16 p_lo[256 * 40];
    __shared__ float s1s[256], s2s[256], srow[256];

    __bf16* F_hi = (__bf16*)u_f32;          // [64][264] bf16
    __bf16* F_lo = F_hi + 64 * 264;

    const int m    = blockIdx.x;
    const int tid  = threadIdx.x;
    const int lane = tid & 63;
    const int wv   = tid >> 6;        // 0..7
    const int nl   = lane & 15;
    const int lq   = lane >> 4;
    const int row2 = tid >> 1;
    const int half = tid & 1;

    {
        const int c = tid & 63;
        float wreg[FIN];
#pragma unroll
        for (int f = 0; f < FIN; ++f) wreg[f] = W[f * 64 + c];
        const float* xm = xin + (size_t)m * NN * FIN;
        for (int i0 = 0; i0 < 32; ++i0) {
            int i = (i0 << 3) | wv;
            float acc = 0.0f;
#pragma unroll
            for (int f4 = 0; f4 < FIN / 4; ++f4) {
                float4 xv = *(const float4*)&xm[i * FIN + f4 * 4];
                acc += xv.x * wreg[f4*4] + xv.y * wreg[f4*4+1]
                     + xv.z * wreg[f4*4+2] + xv.w * wreg[f4*4+3];
            }
            u_f32[i * 68 + c] = acc;
        }
    }
    __syncthreads();

    float hr[32];
    {
        const float* hp = &u_f32[row2 * 68 + half * 32];
        float acc1 = 0.0f, acc2 = 0.0f;
#pragma unroll
        for (int c4 = 0; c4 < 8; ++c4) {
            float4 hv = *(const float4*)&hp[c4 * 4];
            hr[c4*4+0] = hv.x; hr[c4*4+1] = hv.y; hr[c4*4+2] = hv.z; hr[c4*4+3] = hv.w;
            float4 av1 = *(const float4*)&a[half * 32 + c4 * 4];
            float4 av2 = *(const float4*)&a[64 + half * 32 + c4 * 4];
            acc1 += hv.x * av1.x + hv.y * av1.y + hv.z * av1.z + hv.w * av1.w;
            acc2 += hv.x * av2.x + hv.y * av2.y + hv.z * av2.z + hv.w * av2.w;
        }
        acc1 += __shfl_xor(acc1, 1);
        acc2 += __shfl_xor(acc2, 1);
        if (half == 0) { s1s[row2] = acc1; s2s[row2] = acc2; }
    }
    __syncthreads();
    {
#pragma unroll
        for (int cc = 0; cc < 32; ++cc) {
            int c = half * 32 + cc;
            __bf16 hh = bfh(hr[cc]);
            F_hi[c * 264 + row2] = hh;
            F_lo[c * 264 + row2] = bfh(hr[cc] - bf2f(hh));
        }
    }

    const float* adjr = adj + ((size_t)m * NN + row2) * NN + half * 16;
    const float s1v = s1s[row2];
    float srow_acc = 0.0f;

    f32x4 acc[2][4];
#pragma unroll
    for (int mt = 0; mt < 2; ++mt)
#pragma unroll
        for (int nt = 0; nt < 4; ++nt)
            acc[mt][nt] = (f32x4){0.0f, 0.0f, 0.0f, 0.0f};

    float4 adjreg[4];
#pragma unroll
    for (int q = 0; q < 4; ++q) adjreg[q] = *(const float4*)&adjr[q * 4];

    for (int ch = 0; ch < 8; ++ch) {
        {
            float pv[16];
#pragma unroll
            for (int q = 0; q < 4; ++q) {
                float4 av = adjreg[q];
                float4 sv = *(const float4*)&s2s[ch * 32 + half * 16 + q * 4];
                float e0 = s1v + sv.x, e1 = s1v + sv.y, e2 = s1v + sv.z, e3 = s1v + sv.w;
                e0 = (e0 > 0.0f) ? e0 : 0.2f * e0;
                e1 = (e1 > 0.0f) ? e1 : 0.2f * e1;
                e2 = (e2 > 0.0f) ? e2 : 0.2f * e2;
                e3 = (e3 > 0.0f) ? e3 : 0.2f * e3;
                float p0 = (av.x > 0.0f) ? __expf(e0) : 0.0f;
                float p1 = (av.y > 0.0f) ? __expf(e1) : 0.0f;
                float p2 = (av.z > 0.0f) ? __expf(e2) : 0.0f;
                float p3 = (av.w > 0.0f) ? __expf(e3) : 0.0f;
                srow_acc += (p0 + p1) + (p2 + p3);
                pv[q*4+0] = p0; pv[q*4+1] = p1; pv[q*4+2] = p2; pv[q*4+3] = p3;
            }
#pragma unroll
            for (int b = 0; b < 2; ++b) {
                bf16x8 h8, l8;
#pragma unroll
                for (int j = 0; j < 8; ++j) {
                    __bf16 hh = bfh(pv[b*8+j]);
                    h8[j] = hh;
                    l8[j] = bfh(pv[b*8+j] - bf2f(hh));
                }
                *(bf16x8*)&p_hi[row2 * 40 + half * 16 + b * 8] = h8;
                *(bf16x8*)&p_lo[row2 * 40 + half * 16 + b * 8] = l8;
            }
        }
        if (ch < 7) {
#pragma unroll
            for (int q = 0; q < 4; ++q)
                adjreg[q] = *(const float4*)&adjr[(ch + 1) * 32 + q * 4];
        }
        lds_barrier();

        bf16x8 pah[2], pal[2], fbh[4], fbl[4];
#pragma unroll
        for (int mt = 0; mt < 2; ++mt) {
            int row = wv * 32 + mt * 16 + nl;
            pah[mt] = *(const bf16x8*)&p_hi[row * 40 + lq * 8];
            pal[mt] = *(const bf16x8*)&p_lo[row * 40 + lq * 8];
        }
#pragma unroll
        for (int nt = 0; nt < 4; ++nt) {
            int fo = (nt * 16 + nl) * 264 + ch * 32 + lq * 8;
            fbh[nt] = *(const bf16x8*)&F_hi[fo];
            fbl[nt] = *(const bf16x8*)&F_lo[fo];
        }
#pragma unroll
        for (int mt = 0; mt < 2; ++mt)
#pragma unroll
            for (int nt = 0; nt < 4; ++nt)
                acc[mt][nt] = __builtin_amdgcn_mfma_f32_16x16x32_bf16(
                    pah[mt], fbh[nt], acc[mt][nt], 0, 0, 0);
#pragma unroll
        for (int mt = 0; mt < 2; ++mt)
#pragma unroll
            for (int nt = 0; nt < 4; ++nt)
                acc[mt][nt] = __builtin_amdgcn_mfma_f32_16x16x32_bf16(
                    pal[mt], fbh[nt], acc[mt][nt], 0, 0, 0);
#pragma unroll
        for (int mt = 0; mt < 2; ++mt)
#pragma unroll
            for (int nt = 0; nt < 4; ++nt)
                acc[mt][nt] = __builtin_amdgcn_mfma_f32_16x16x32_bf16(
                    pah[mt], fbl[nt], acc[mt][nt], 0, 0, 0);

        lds_barrier();
    }

    {
        float sr = srow_acc + __shfl_xor(srow_acc, 1);
        if (half == 0) srow[row2] = sr;
    }
    __syncthreads();

    float gm[4], bt[4];
#pragma unroll
    for (int nt = 0; nt < 4; ++nt) {
        gm[nt] = gamma_[nt * 16 + nl];
        bt[nt] = beta_[nt * 16 + nl];
    }
#pragma unroll
    for (int mt = 0; mt < 2; ++mt) {
#pragma unroll
        for (int r = 0; r < 4; ++r) {
            int row = wv * 32 + mt * 16 + lq * 4 + r;
            float rinv = fast_rcp(srow[row]);
            float v[4];
            float sm = 0.0f, sq = 0.0f;
#pragma unroll
            for (int nt = 0; nt < 4; ++nt) {
                v[nt] = acc[mt][nt][r] * rinv;
                sm += v[nt]; sq += v[nt] * v[nt];
            }
#pragma unroll
            for (int off = 1; off < 16; off <<= 1) {
                sm += __shfl_xor(sm, off);
                sq += __shfl_xor(sq, off);
            }
            float mu  = sm * (1.0f / 64.0f);
            float var = sq * (1.0f / 64.0f) - mu * mu;
            float rs  = rsqrtf(var + 1e-5f);
            float* gp = &gout[((size_t)m * NN + row) * 64];
#pragma unroll
            for (int nt = 0; nt < 4; ++nt) {
                float hn = (v[nt] - mu) * rs * gm[nt] + bt[nt];
                gp[nt * 16 + nl] = (hn > 0.0f) ? hn : (__expf(hn) - 1.0f);
            }
        }
    }
}

// ---------------------------------------------------------------------------
// residual + gate*g, reshaped to sequence layout [B*N][T][H] (unchanged)
// ---------------------------------------------------------------------------
__global__ __launch_bounds__(256) void combine_kernel(
    const float* __restrict__ x,      // [B*S*N][32]
    const float* __restrict__ g1,     // [B*S*N][64]
    const float* __restrict__ res_W,  // [32][64]
    const float* __restrict__ res_b,  // [64]
    const float* __restrict__ alpha_p,
    float* __restrict__ seqout)       // [B*N][T][64]
{
    int row = blockIdx.x * 4 + (threadIdx.x >> 6);
    int h = threadIdx.x & 63;
    int mg = row >> 8, n = row & 255;
    int b = mg >> 6, s = mg & 63;
    const float* xr = x + (size_t)row * 32;
    float acc = res_b[h];
#pragma unroll
    for (int f4 = 0; f4 < 8; ++f4) {
        float4 xv = *(const float4*)&xr[f4 * 4];
        acc += xv.x * res_W[(f4*4    ) * 64 + h] + xv.y * res_W[(f4*4 + 1) * 64 + h]
             + xv.z * res_W[(f4*4 + 2) * 64 + h] + xv.w * res_W[(f4*4 + 3) * 64 + h];
    }
    float alpha = fminf(fmaxf(alpha_p[0], 0.0f), 1.0f);
    acc += alpha * g1[(size_t)row * 64 + h];
    seqout[(((size_t)(b * NN + n)) * TT + s) * 64 + h] = acc;
}

// ---------------------------------------------------------------------------
// W pre-convert: Wih[2][K][256] fp32 -> fragment-ordered bf16 hi/lo.
// idx = ((dir*NKC + kc)*16 + ng)*512 + g*128 + nl*8 + j
//   holds W[dir][kc*32 + 8*g + j][ng*16 + nl].
// ---------------------------------------------------------------------------
template<int K>
__global__ __launch_bounds__(256) void wcvt_kernel(
    const float* __restrict__ Wih, __bf16* __restrict__ Wh, __bf16* __restrict__ Wl)
{
    constexpr int NKC = K / 32;
    int idx = blockIdx.x * 256 + threadIdx.x;
    int j   = idx & 7;
    int nl  = (idx >> 3) & 15;
    int g   = (idx >> 7) & 3;
    int ng  = (idx >> 9) & 15;
    int rest = idx >> 13;                 // dir*NKC + kc
    int kc  = rest & (NKC - 1);
    int dir = rest / NKC;
    int k = kc * 32 + g * 8 + j;
    int n = ng * 16 + nl;
    float x = Wih[((size_t)dir * K + k) * 256 + n];
    __bf16 h = bfh(x);
    Wh[idx] = h;
    Wl[idx] = bfh(x - bf2f(h));
}

// ---------------------------------------------------------------------------
// Whh pre-convert (both layers): out [layer][hi 32768 | lo 32768] bf16.
// ---------------------------------------------------------------------------
__global__ __launch_bounds__(256) void whhcvt_kernel(
    const float* __restrict__ W0, const float* __restrict__ W1,
    __bf16* __restrict__ outw)
{
    int idx = blockIdx.x * 256 + threadIdx.x;   // 0..65535
    int lay = idx >> 15;
    int r   = idx & 32767;
    int j   = r & 7;
    int nl  = (r >> 3) & 15;
    int g   = (r >> 7) & 3;
    int ng  = (r >> 9) & 15;
    int rest = r >> 13;                  // dir*2 + kc
    int kc  = rest & 1;
    int dir = rest >> 1;
    int k = kc * 32 + g * 8 + j;
    int n = ng * 16 + nl;
    const float* W = lay ? W1 : W0;
    float x = W[((size_t)dir * 64 + k) * 256 + n];
    __bf16 h = bfh(x);
    outw[lay * 65536 + r]         = h;
    outw[lay * 65536 + 32768 + r] = bfh(x - bf2f(h));
}

// ---------------------------------------------------------------------------
// FUSED LSTM v12b: recurrence + input-GEMM in one kernel (xg never hits HBM).
// v12 FAILED from a prologue race: the x-LDS zero-init and the x(0) data
// staging were unordered cross-wave writes to the same addresses. Fix: one
// __syncthreads() between them. Everything else identical to v12.
// ---------------------------------------------------------------------------
template<int K>
__global__ __launch_bounds__(256, 2) void lstm_fused_kernel(
    const float* __restrict__ xin,    // [NSEQ][T][K]
    const __bf16* __restrict__ whhf,  // [hi 32768 | lo 32768]
    const __bf16* __restrict__ wih_h, // frag-ordered [2*NKC*16][512]
    const __bf16* __restrict__ wih_l,
    const float* __restrict__ bih,    // [2][256]
    const float* __restrict__ bhh,    // [2][256]
    float* __restrict__ out,
    int write_all)
{
    constexpr int NKC = K / 32;
    constexpr int XPT = (4 * K) / 256;   // x values per thread (1 or 2)

    const int tid  = threadIdx.x;
    const int wv   = tid >> 6;
    const int lane = tid & 63;
    const int nl   = lane & 15;
    const int lq   = lane >> 4;

    const int bid  = blockIdx.x;      // grid 512
    const int dir  = bid & 1;
    const int seq0 = (bid >> 1) * 4;

    // Whh B-frags (hi+lo) in VGPRs
    const __bf16* wh = whhf;
    const __bf16* wl = whhf + 32768;
    bf16x8 hbh[2][4], hbl[2][4];
#pragma unroll
    for (int kc = 0; kc < 2; ++kc)
#pragma unroll
        for (int g = 0; g < 4; ++g) {
            size_t fb = ((size_t)((dir * 2 + kc) * 16 + g * 4 + wv)) * 512 + lane * 8;
            hbh[kc][g] = *(const bf16x8*)(wh + fb);
            hbl[kc][g] = *(const bf16x8*)(wl + fb);
        }
    // Wih-hi B-frags in VGPRs; lo streamed per step
    bf16x8 wbh[NKC][4];
#pragma unroll
    for (int kc = 0; kc < NKC; ++kc)
#pragma unroll
        for (int g = 0; g < 4; ++g) {
            size_t fb = ((size_t)((dir * NKC + kc) * 16 + g * 4 + wv)) * 512 + lane * 8;
            wbh[kc][g] = *(const bf16x8*)(wih_h + fb);
        }
    const __bf16* wlb[4];
#pragma unroll
    for (int g = 0; g < 4; ++g)
        wlb[g] = wih_l + ((size_t)(dir * NKC) * 16 + g * 4 + wv) * 512 + lane * 8;

    // LDS: h (2 parity x 16 x 64) + x (2 parity x 16 x K), bf16 hi/lo
    __shared__ __align__(16) __bf16 h_hi[2048];
    __shared__ __align__(16) __bf16 h_lo[2048];
    __shared__ __align__(16) __bf16 x_hi[32 * K];
    __shared__ __align__(16) __bf16 x_lo[32 * K];
    {
        uint4 z = {0, 0, 0, 0};
        *(uint4*)&h_hi[tid * 8] = z;
        *(uint4*)&h_lo[tid * 8] = z;
#pragma unroll
        for (int i = 0; i < K / 64; ++i) {
            *(uint4*)&x_hi[tid * 8 + i * 2048] = z;
            *(uint4*)&x_lo[tid * 8 + i * 2048] = z;
        }
    }
    __syncthreads();   // RACE FIX: zero-init visible before x(0) data staging

    const int k   = wv * 16 + nl;     // this lane's cell hidden index
    const int g8k = k >> 3;

    float bias4[4];
#pragma unroll
    for (int g = 0; g < 4; ++g)
        bias4[g] = bih[dir * 256 + g * 64 + k] + bhh[dir * 256 + g * 64 + k];

    float c = 0.0f;

    // x staging: thread -> XPT values (s, kx)
    int xoff[XPT];
    const float* px[XPT];
    const int trow0 = dir ? (TT - 1) : 0;
    const int dstepx = dir ? -K : K;
#pragma unroll
    for (int i = 0; i < XPT; ++i) {
        int v = tid + i * 256;
        int s = v / K, kx = v & (K - 1);
        xoff[i] = s * K + (((kx >> 3) ^ s) * 8) + (kx & 7);
        px[i] = xin + ((size_t)(seq0 + s) * TT + trow0) * K + kx;
    }
    auto issue_x = [&](float (&d)[XPT]) {
#pragma unroll
        for (int i = 0; i < XPT; ++i) { d[i] = *px[i]; px[i] += dstepx; }
    };
    auto write_x = [&](float (&d)[XPT], int pbuf) {
#pragma unroll
        for (int i = 0; i < XPT; ++i) {
            __bf16 hh = bfh(d[i]);
            x_hi[pbuf * 16 * K + xoff[i]] = hh;
            x_lo[pbuf * 16 * K + xoff[i]] = bfh(d[i] - bf2f(hh));
        }
    };

    // out stepping pointer (cell lane owns (s=lq, k))
    float* pout = out + (((size_t)(seq0 + lq)) * TT + trow0) * 128 + dir * 64 + k;
    const int ostep = dir ? -128 : 128;

    // prologue: x(0) -> buf0; x(1) in flight
    float xr0[XPT];
    issue_x(xr0);
    write_x(xr0, 0);                      // implicit vmcnt wait at use
    float xrA[XPT], xrB[XPT];
    issue_x(xrA);                         // x(1), converted at step 0
    lds_barrier();

    int buf = 0;
    auto step_body = [&](int step, float (&xcur)[XPT], float (&xnext)[XPT]) {
        // A-frags: h(step)
        const int aofh0 = buf * 1024 + nl * 64 + (((0 + lq) ^ (nl & 7)) * 8);
        const int aofh1 = buf * 1024 + nl * 64 + (((4 + lq) ^ (nl & 7)) * 8);
        bf16x8 ah0 = *(const bf16x8*)&h_hi[aofh0];
        bf16x8 ah1 = *(const bf16x8*)&h_hi[aofh1];
        bf16x8 al0 = *(const bf16x8*)&h_lo[aofh0];
        bf16x8 al1 = *(const bf16x8*)&h_lo[aofh1];
        // A-frags: x(step)
        bf16x8 xh[NKC], xl[NKC];
#pragma unroll
        for (int kc = 0; kc < NKC; ++kc) {
            int xo = buf * 16 * K + nl * K + ((((kc * 4) + lq) ^ (nl & 7)) * 8);
            xh[kc] = *(const bf16x8*)&x_hi[xo];
            xl[kc] = *(const bf16x8*)&x_lo[xo];
        }

        // stream first Wih-lo chunk; prefetch next x
        bf16x8 wblq[2][4];
#pragma unroll
        for (int g = 0; g < 4; ++g)
            wblq[0][g] = *(const bf16x8*)(wlb[g]);
        if (step + 2 < TT) issue_x(xnext);

        f32x4 acc[4];
#pragma unroll
        for (int g = 0; g < 4; ++g) acc[g] = (f32x4){0.0f, 0.0f, 0.0f, 0.0f};
        // Whh terms (6 per gate)
#pragma unroll
        for (int g = 0; g < 4; ++g)
            acc[g] = __builtin_amdgcn_mfma_f32_16x16x32_bf16(ah0, hbh[0][g], acc[g], 0, 0, 0);
#pragma unroll
        for (int g = 0; g < 4; ++g)
            acc[g] = __builtin_amdgcn_mfma_f32_16x16x32_bf16(ah1, hbh[1][g], acc[g], 0, 0, 0);
#pragma unroll
        for (int g = 0; g < 4; ++g)
            acc[g] = __builtin_amdgcn_mfma_f32_16x16x32_bf16(al0, hbh[0][g], acc[g], 0, 0, 0);
#pragma unroll
        for (int g = 0; g < 4; ++g)
            acc[g] = __builtin_amdgcn_mfma_f32_16x16x32_bf16(al1, hbh[1][g], acc[g], 0, 0, 0);
#pragma unroll
        for (int g = 0; g < 4; ++g)
            acc[g] = __builtin_amdgcn_mfma_f32_16x16x32_bf16(ah0, hbl[0][g], acc[g], 0, 0, 0);
#pragma unroll
        for (int g = 0; g < 4; ++g)
            acc[g] = __builtin_amdgcn_mfma_f32_16x16x32_bf16(ah1, hbl[1][g], acc[g], 0, 0, 0);
        // Wih terms: xh*wbh, xl*wbh (hi in regs)
#pragma unroll
        for (int kc = 0; kc < NKC; ++kc)
#pragma unroll
            for (int g = 0; g < 4; ++g)
                acc[g] = __builtin_amdgcn_mfma_f32_16x16x32_bf16(xh[kc], wbh[kc][g], acc[g], 0, 0, 0);
#pragma unroll
        for (int kc = 0; kc < NKC; ++kc)
#pragma unroll
            for (int g = 0; g < 4; ++g)
                acc[g] = __builtin_amdgcn_mfma_f32_16x16x32_bf16(xl[kc], wbh[kc][g], acc[g], 0, 0, 0);
        // Wih-lo terms, streamed double-buffered
#pragma unroll
        for (int kc = 0; kc < NKC; ++kc) {
            if (kc + 1 < NKC)
#pragma unroll
                for (int g = 0; g < 4; ++g)
                    wblq[(kc + 1) & 1][g] = *(const bf16x8*)(wlb[g] + (kc + 1) * 8192);
#pragma unroll
            for (int g = 0; g < 4; ++g)
                acc[g] = __builtin_amdgcn_mfma_f32_16x16x32_bf16(xh[kc], wblq[kc & 1][g], acc[g], 0, 0, 0);
        }

        // redistribute: lane (lq,nl) takes acc[g][r=lq] from lane nl
        float pre4[4];
#pragma unroll
        for (int g = 0; g < 4; ++g) {
            float b0 = __shfl(acc[g][0], nl);
            float b1 = __shfl(acc[g][1], nl);
            float b2 = __shfl(acc[g][2], nl);
            float b3 = __shfl(acc[g][3], nl);
            float v01 = (lq & 1) ? b1 : b0;
            float v23 = (lq & 1) ? b3 : b2;
            pre4[g] = (lq & 2) ? v23 : v01;
        }

        // cell update: one cell per lane (s=lq, k)
        float iv = sigmoid_f(pre4[0] + bias4[0]);
        float fv = sigmoid_f(pre4[1] + bias4[1]);
        float gv = tanh_f  (pre4[2] + bias4[2]);
        float ov = sigmoid_f(pre4[3] + bias4[3]);
        c = fv * c + iv * gv;
        float h = ov * tanh_f(c);
        int off = (buf ^ 1) * 1024 + lq * 64 + ((g8k ^ lq) * 8) + (k & 7);
        __bf16 hh = bfh(h);
        h_hi[off] = hh;
        h_lo[off] = bfh(h - bf2f(hh));
        if (write_all)
            pout[0] = h;
        else if (step == TT - 1)
            out[(size_t)(seq0 + lq) * 128 + dir * 64 + k] = h;
        pout += ostep;
        if (step + 1 < TT) write_x(xcur, buf ^ 1);     // x(step+1) -> next buf
        lds_barrier();
        buf ^= 1;
    };

    for (int step = 0; step < TT; step += 2) {
        step_body(step,     xrA, xrB);
        step_body(step + 1, xrB, xrA);
    }
}

// ---------------------------------------------------------------------------
__global__ __launch_bounds__(256) void fc_kernel(
    const float* __restrict__ fin,   // [NSEQ][128]
    const float* __restrict__ fc_W,  // [128]
    const float* __restrict__ fc_b,  // [1]
    float* __restrict__ outp)        // [NSEQ]
{
    int s = blockIdx.x * 256 + threadIdx.x;
    const float* fr = fin + (size_t)s * 128;
    float acc = fc_b[0];
#pragma unroll
    for (int k4 = 0; k4 < 32; ++k4) {
        float4 fv = *(const float4*)&fr[k4 * 4];
        float4 wv2 = *(const float4*)&fc_W[k4 * 4];
        acc += fv.x * wv2.x + fv.y * wv2.y + fv.z * wv2.z + fv.w * wv2.w;
    }
    outp[s] = acc;
}

// ---------------------------------------------------------------------------
extern "C" void kernel_launch(void* const* d_in, const int* in_sizes, int n_in,
                              void* d_out, int out_size, void* d_ws, size_t ws_size,
                              hipStream_t stream) {
    const float* x       = (const float*)d_in[0];
    const float* adj     = (const float*)d_in[1];
    const float* gat0_W  = (const float*)d_in[2];
    const float* gat0_a  = (const float*)d_in[3];
    const float* gat0_g  = (const float*)d_in[4];
    const float* gat0_b  = (const float*)d_in[5];
    const float* gat1_W  = (const float*)d_in[6];
    const float* gat1_a  = (const float*)d_in[7];
    const float* gat1_g  = (const float*)d_in[8];
    const float* gat1_b  = (const float*)d_in[9];
    const float* res_W   = (const float*)d_in[10];
    const float* res_b   = (const float*)d_in[11];
    const float* alpha_g = (const float*)d_in[12];
    const float* l0_Wih  = (const float*)d_in[13];
    const float* l0_Whh  = (const float*)d_in[14];
    const float* l0_bih  = (const float*)d_in[15];
    const float* l0_bhh  = (const float*)d_in[16];
    const float* l1_Wih  = (const float*)d_in[17];
    const float* l1_Whh  = (const float*)d_in[18];
    const float* l1_bih  = (const float*)d_in[19];
    const float* l1_bhh  = (const float*)d_in[20];
    const float* fc_W    = (const float*)d_in[21];
    const float* fc_b    = (const float*)d_in[22];

    float* ws = (float*)d_ws;
    float* g0    = ws;                    // [M][N][64]
    float* g1    = ws + 4194304;          // [M][N][64]
    float* seq   = ws + 8388608;          // [B*N][T][64] (LIVE through lstm L0)
    float* o1    = ws;                    // [NSEQ][T][128] reuse g0+g1 (dead)
    float* fin   = ws + 46137344;         // [NSEQ][128]

    // weight frags in the old xg region (now free)
    __bf16* w0h  = (__bf16*)(ws + 12582912);
    __bf16* w0l  = w0h + 32768;           // 2*64*256
    __bf16* w1h  = w0l + 32768;
    __bf16* w1l  = w1h + 65536;           // 2*128*256
    __bf16* whhf = w1l + 65536;           // [2 layers][hi 32768 | lo 32768]

    wcvt_kernel<64><<<128, 256, 0, stream>>>(l0_Wih, w0h, w0l);
    wcvt_kernel<128><<<256, 256, 0, stream>>>(l1_Wih, w1h, w1l);
    whhcvt_kernel<<<256, 256, 0, stream>>>(l0_Whh, l1_Whh, whhf);
    gat_kernel<32><<<MM, 512, 0, stream>>>(x, adj, gat0_W, gat0_a, gat0_g, gat0_b, g0);
    gat_kernel<64><<<MM, 512, 0, stream>>>(g0, adj, gat1_W, gat1_a, gat1_g, gat1_b, g1);
    combine_kernel<<<(BB*SS*NN)/4, 256, 0, stream>>>(x, g1, res_W, res_b, alpha_g, seq);
    lstm_fused_kernel<64><<<512, 256, 0, stream>>>(seq, whhf, w0h, w0l,
                                                   l0_bih, l0_bhh, o1, 1);
    lstm_fused_kernel<128><<<512, 256, 0, stream>>>(o1, whhf + 65536, w1h, w1l,
                                                    l1_bih, l1_bhh, fin, 0);
    fc_kernel<<<NSEQ/256, 256, 0, stream>>>(fin, fc_W, fc_b, (float*)d_out);
}